// Round 3
// baseline (246.910 us; speedup 1.0000x reference)
//
#include <hip/hip_runtime.h>
#include <hip/hip_bf16.h>

// CZ gate: out[i] = state[i], sign flipped iff bits c2,t2 of the flat index
// are both set (D = 2^n, so flat-index bits == column-index bits).
// Pure 1 GiB R+W streaming op; roofline = float4-copy ceiling ~6.3 TB/s.
//
// Round-3 change vs r2 (197 us, 5.44 TB/s): 4x unrolled grid-stride loop
// with 4 independent nontemporal loads issued back-to-back before the 4
// stores -> more outstanding VMEM requests per wave (MLP), hiding HBM
// latency better. n4 = 2^25, stride = 2^19 -> exactly 16 unrolled iters,
// empty tail. Occupancy already 100% (VGPR=8, 2048 blocks x 256 thr).

typedef int  v4i __attribute__((ext_vector_type(4)));
typedef unsigned int u32;

__device__ __forceinline__ int cz_mask(u32 b, int c2, int t2) {
    return (int)((((b >> c2) & (b >> t2)) & 1u) << 31);
}

__global__ void __launch_bounds__(256)
cz_kernel(const v4i* __restrict__ in, v4i* __restrict__ out,
          const int* __restrict__ p_ctrl, const int* __restrict__ p_tgt,
          const int* __restrict__ p_nq, int n4) {
    const int nq = *p_nq;
    const int c2 = nq - *p_ctrl - 1;
    const int t2 = nq - *p_tgt - 1;

    const int stride = gridDim.x * blockDim.x;
    int i = blockIdx.x * blockDim.x + threadIdx.x;

    if (c2 >= 2 && t2 >= 2) {
        // sign uniform across each aligned group of 4 floats
        for (; i + 3 * stride < n4; i += 4 * stride) {
            const int i0 = i, i1 = i + stride, i2 = i + 2 * stride, i3 = i + 3 * stride;
            v4i v0 = __builtin_nontemporal_load(&in[i0]);
            v4i v1 = __builtin_nontemporal_load(&in[i1]);
            v4i v2 = __builtin_nontemporal_load(&in[i2]);
            v4i v3 = __builtin_nontemporal_load(&in[i3]);
            const int m0 = cz_mask((u32)i0 << 2, c2, t2);
            const int m1 = cz_mask((u32)i1 << 2, c2, t2);
            const int m2 = cz_mask((u32)i2 << 2, c2, t2);
            const int m3 = cz_mask((u32)i3 << 2, c2, t2);
            v0.x ^= m0; v0.y ^= m0; v0.z ^= m0; v0.w ^= m0;
            v1.x ^= m1; v1.y ^= m1; v1.z ^= m1; v1.w ^= m1;
            v2.x ^= m2; v2.y ^= m2; v2.z ^= m2; v2.w ^= m2;
            v3.x ^= m3; v3.y ^= m3; v3.z ^= m3; v3.w ^= m3;
            __builtin_nontemporal_store(v0, &out[i0]);
            __builtin_nontemporal_store(v1, &out[i1]);
            __builtin_nontemporal_store(v2, &out[i2]);
            __builtin_nontemporal_store(v3, &out[i3]);
        }
        for (; i < n4; i += stride) {  // tail (empty for 2^25 / 2^19)
            v4i v = __builtin_nontemporal_load(&in[i]);
            const int m = cz_mask((u32)i << 2, c2, t2);
            v.x ^= m; v.y ^= m; v.z ^= m; v.w ^= m;
            __builtin_nontemporal_store(v, &out[i]);
        }
    } else {
        // general path: per-element sign (c2 or t2 inside the low 2 bits)
        for (; i < n4; i += stride) {
            v4i v = __builtin_nontemporal_load(&in[i]);
            const u32 b = (u32)i << 2;
            v.x ^= cz_mask(b,     c2, t2);
            v.y ^= cz_mask(b + 1, c2, t2);
            v.z ^= cz_mask(b + 2, c2, t2);
            v.w ^= cz_mask(b + 3, c2, t2);
            __builtin_nontemporal_store(v, &out[i]);
        }
    }
}

extern "C" void kernel_launch(void* const* d_in, const int* in_sizes, int n_in,
                              void* d_out, int out_size, void* d_ws, size_t ws_size,
                              hipStream_t stream) {
    const float* state = (const float*)d_in[0];
    const int* p_ctrl  = (const int*)d_in[1];
    const int* p_tgt   = (const int*)d_in[2];
    const int* p_nq    = (const int*)d_in[3];
    float* out = (float*)d_out;

    const long long n = (long long)in_sizes[0];   // 16384 * 8192 = 2^27
    const int n4 = (int)(n >> 2);                 // 2^25

    const int block = 256;
    long long want = ((long long)n4 + block - 1) / block;
    int grid = (int)(want < 2048 ? want : 2048);  // 8 blocks/CU -> 32 waves/CU

    cz_kernel<<<grid, block, 0, stream>>>(
        (const v4i*)state, (v4i*)out, p_ctrl, p_tgt, p_nq, n4);
}

// Round 4
// 190.142 us; speedup vs baseline: 1.2986x; 1.2986x over previous
//
#include <hip/hip_runtime.h>
#include <hip/hip_bf16.h>

// CZ gate: out[i] = state[i], sign flipped iff bits c2,t2 of the flat index
// are both set (D = 2^n, so flat-index bits == column-index bits).
// Pure 1 GiB R+W streaming op; roofline = float4-copy ceiling ~6.3 TB/s.
//
// Round-4: r3's 4x unroll at stride-separated addresses REGRESSED (247 us) --
// 8192 concurrent 8MB-apart streams killed DRAM locality. This round keeps
// r2's structure (197 us) but unrolls 2x at BLOCK-contiguous offsets
// (i, i+256): per-block footprint stays one contiguous 8 KiB region per
// iteration, stream count stays 2048, while each wave gets 2 loads in
// flight. n4 = 2^25, step = 2^20 -> exactly 32 iterations, empty tail.

typedef int  v4i __attribute__((ext_vector_type(4)));
typedef unsigned int u32;

__device__ __forceinline__ int cz_mask(u32 b, int c2, int t2) {
    return (int)((((b >> c2) & (b >> t2)) & 1u) << 31);
}

__global__ void __launch_bounds__(256)
cz_kernel(const v4i* __restrict__ in, v4i* __restrict__ out,
          const int* __restrict__ p_ctrl, const int* __restrict__ p_tgt,
          const int* __restrict__ p_nq, int n4) {
    const int nq = *p_nq;
    const int c2 = nq - *p_ctrl - 1;
    const int t2 = nq - *p_tgt - 1;

    const int nthreads = gridDim.x * blockDim.x;   // 2^19

    if (c2 >= 2 && t2 >= 2) {
        // sign uniform across each aligned group of 4 floats
        const int step = nthreads * 2;             // 2^20
        int i = blockIdx.x * (blockDim.x * 2) + threadIdx.x;
        for (; i + blockDim.x < n4; i += step) {
            const int i0 = i;
            const int i1 = i + blockDim.x;         // adjacent 4 KiB chunk
            v4i v0 = __builtin_nontemporal_load(&in[i0]);
            v4i v1 = __builtin_nontemporal_load(&in[i1]);
            const int m0 = cz_mask((u32)i0 << 2, c2, t2);
            const int m1 = cz_mask((u32)i1 << 2, c2, t2);
            v0.x ^= m0; v0.y ^= m0; v0.z ^= m0; v0.w ^= m0;
            v1.x ^= m1; v1.y ^= m1; v1.z ^= m1; v1.w ^= m1;
            __builtin_nontemporal_store(v0, &out[i0]);
            __builtin_nontemporal_store(v1, &out[i1]);
        }
        for (; i < n4; i += nthreads) {            // tail (empty for 2^25)
            v4i v = __builtin_nontemporal_load(&in[i]);
            const int m = cz_mask((u32)i << 2, c2, t2);
            v.x ^= m; v.y ^= m; v.z ^= m; v.w ^= m;
            __builtin_nontemporal_store(v, &out[i]);
        }
    } else {
        // general path: per-element sign (c2 or t2 inside the low 2 bits)
        for (int i = blockIdx.x * blockDim.x + threadIdx.x; i < n4; i += nthreads) {
            v4i v = __builtin_nontemporal_load(&in[i]);
            const u32 b = (u32)i << 2;
            v.x ^= cz_mask(b,     c2, t2);
            v.y ^= cz_mask(b + 1, c2, t2);
            v.z ^= cz_mask(b + 2, c2, t2);
            v.w ^= cz_mask(b + 3, c2, t2);
            __builtin_nontemporal_store(v, &out[i]);
        }
    }
}

extern "C" void kernel_launch(void* const* d_in, const int* in_sizes, int n_in,
                              void* d_out, int out_size, void* d_ws, size_t ws_size,
                              hipStream_t stream) {
    const float* state = (const float*)d_in[0];
    const int* p_ctrl  = (const int*)d_in[1];
    const int* p_tgt   = (const int*)d_in[2];
    const int* p_nq    = (const int*)d_in[3];
    float* out = (float*)d_out;

    const long long n = (long long)in_sizes[0];   // 16384 * 8192 = 2^27
    const int n4 = (int)(n >> 2);                 // 2^25

    const int block = 256;
    long long want = ((long long)n4 + block - 1) / block;
    int grid = (int)(want < 2048 ? want : 2048);  // 8 blocks/CU -> 32 waves/CU

    cz_kernel<<<grid, block, 0, stream>>>(
        (const v4i*)state, (v4i*)out, p_ctrl, p_tgt, p_nq, n4);
}

// Round 5
// 179.520 us; speedup vs baseline: 1.3754x; 1.0592x over previous
//
#include <hip/hip_runtime.h>
#include <hip/hip_bf16.h>

// CZ gate: out[i] = state[i], sign flipped iff bits c2,t2 of the flat index
// are both set (D = 2^n, so flat-index bits == column-index bits).
// Pure 1 GiB R+W streaming op; roofline = float4-copy ceiling ~6.3 TB/s.
//
// History: r2 plain NT loop = 197 us; r3 4x unroll at 8MB-separated
// addresses REGRESSED (247 us, DRAM locality); r4 2x unroll at
// block-contiguous offsets = 190 us (5.65 TB/s, 90% of copy ceiling).
// Round-5: extend the proven mechanism to 4x block-contiguous offsets
// (i, i+256, i+512, i+768): per-block footprint one contiguous 16 KiB
// region per iteration, stream count stays 2048, 4 loads in flight per
// wave. n4 = 2^25, step = 2^21 -> exactly 16 iterations, empty tail.

typedef int  v4i __attribute__((ext_vector_type(4)));
typedef unsigned int u32;

__device__ __forceinline__ int cz_mask(u32 b, int c2, int t2) {
    return (int)((((b >> c2) & (b >> t2)) & 1u) << 31);
}

__global__ void __launch_bounds__(256)
cz_kernel(const v4i* __restrict__ in, v4i* __restrict__ out,
          const int* __restrict__ p_ctrl, const int* __restrict__ p_tgt,
          const int* __restrict__ p_nq, int n4) {
    const int nq = *p_nq;
    const int c2 = nq - *p_ctrl - 1;
    const int t2 = nq - *p_tgt - 1;

    const int nthreads = gridDim.x * blockDim.x;   // 2^19

    if (c2 >= 2 && t2 >= 2) {
        // sign uniform across each aligned group of 4 floats
        const int step = nthreads * 4;             // 2^21
        int i = blockIdx.x * (blockDim.x * 4) + threadIdx.x;
        for (; i + 3 * blockDim.x < n4; i += step) {
            const int i0 = i;
            const int i1 = i +     blockDim.x;     // +4 KiB
            const int i2 = i + 2 * blockDim.x;     // +8 KiB
            const int i3 = i + 3 * blockDim.x;     // +12 KiB
            v4i v0 = __builtin_nontemporal_load(&in[i0]);
            v4i v1 = __builtin_nontemporal_load(&in[i1]);
            v4i v2 = __builtin_nontemporal_load(&in[i2]);
            v4i v3 = __builtin_nontemporal_load(&in[i3]);
            const int m0 = cz_mask((u32)i0 << 2, c2, t2);
            const int m1 = cz_mask((u32)i1 << 2, c2, t2);
            const int m2 = cz_mask((u32)i2 << 2, c2, t2);
            const int m3 = cz_mask((u32)i3 << 2, c2, t2);
            v0.x ^= m0; v0.y ^= m0; v0.z ^= m0; v0.w ^= m0;
            v1.x ^= m1; v1.y ^= m1; v1.z ^= m1; v1.w ^= m1;
            v2.x ^= m2; v2.y ^= m2; v2.z ^= m2; v2.w ^= m2;
            v3.x ^= m3; v3.y ^= m3; v3.z ^= m3; v3.w ^= m3;
            __builtin_nontemporal_store(v0, &out[i0]);
            __builtin_nontemporal_store(v1, &out[i1]);
            __builtin_nontemporal_store(v2, &out[i2]);
            __builtin_nontemporal_store(v3, &out[i3]);
        }
        for (; i < n4; i += nthreads) {            // tail (empty for 2^25)
            v4i v = __builtin_nontemporal_load(&in[i]);
            const int m = cz_mask((u32)i << 2, c2, t2);
            v.x ^= m; v.y ^= m; v.z ^= m; v.w ^= m;
            __builtin_nontemporal_store(v, &out[i]);
        }
    } else {
        // general path: per-element sign (c2 or t2 inside the low 2 bits)
        for (int i = blockIdx.x * blockDim.x + threadIdx.x; i < n4; i += nthreads) {
            v4i v = __builtin_nontemporal_load(&in[i]);
            const u32 b = (u32)i << 2;
            v.x ^= cz_mask(b,     c2, t2);
            v.y ^= cz_mask(b + 1, c2, t2);
            v.z ^= cz_mask(b + 2, c2, t2);
            v.w ^= cz_mask(b + 3, c2, t2);
            __builtin_nontemporal_store(v, &out[i]);
        }
    }
}

extern "C" void kernel_launch(void* const* d_in, const int* in_sizes, int n_in,
                              void* d_out, int out_size, void* d_ws, size_t ws_size,
                              hipStream_t stream) {
    const float* state = (const float*)d_in[0];
    const int* p_ctrl  = (const int*)d_in[1];
    const int* p_tgt   = (const int*)d_in[2];
    const int* p_nq    = (const int*)d_in[3];
    float* out = (float*)d_out;

    const long long n = (long long)in_sizes[0];   // 16384 * 8192 = 2^27
    const int n4 = (int)(n >> 2);                 // 2^25

    const int block = 256;
    long long want = ((long long)n4 + block - 1) / block;
    int grid = (int)(want < 2048 ? want : 2048);  // 8 blocks/CU -> 32 waves/CU

    cz_kernel<<<grid, block, 0, stream>>>(
        (const v4i*)state, (v4i*)out, p_ctrl, p_tgt, p_nq, n4);
}